// Round 3
// baseline (88.046 us; speedup 1.0000x reference)
//
#include <hip/hip_runtime.h>

// out[0] = mean(|pred - mask|) over 16Mi fp32 elements (the Gaussian-conv
// loop in the reference is dead code). Memory-bound streaming reduction.
//
// Round-3 change: round-1's grid-stride kernel already streams at ~5.4 TB/s
// (near the read ceiling); the slack is the 2nd dispatch + gap (~5 us).
// Fuse the final reduce via threadfence + last-block-done counter.
// Counter is zeroed with a 4-byte hipMemsetAsync (graph-capture legal).
// Deterministic: partial sums are per-block deterministic; the last block
// sums partial[0..2047] in fixed order (atomic only elects the finisher).

#define N_TOTAL (16u * 1024u * 1024u)   // 16,777,216 elements
#define NBLOCKS 2048
#define NTHREADS 256

__global__ __launch_bounds__(NTHREADS) void abs_diff_mean(
    const float4* __restrict__ pred,
    const float4* __restrict__ mask,
    float* __restrict__ partial,
    unsigned* __restrict__ counter,
    float* __restrict__ out) {
    const int n4 = (int)(N_TOTAL / 4);  // 4,194,304 float4
    float acc = 0.0f;
    for (int i = blockIdx.x * blockDim.x + threadIdx.x; i < n4;
         i += gridDim.x * blockDim.x) {
        float4 p = pred[i];
        float4 m = mask[i];
        acc += fabsf(p.x - m.x) + fabsf(p.y - m.y) +
               fabsf(p.z - m.z) + fabsf(p.w - m.w);
    }
    // wave-64 shuffle reduce
    #pragma unroll
    for (int off = 32; off > 0; off >>= 1)
        acc += __shfl_down(acc, off, 64);

    __shared__ float s[NTHREADS / 64];
    __shared__ bool last;
    const int lane = threadIdx.x & 63;
    const int wid  = threadIdx.x >> 6;
    if (lane == 0) s[wid] = acc;
    __syncthreads();
    if (threadIdx.x == 0) {
        partial[blockIdx.x] = (s[0] + s[1]) + (s[2] + s[3]);  // fixed order
        __threadfence();  // make partial visible device-wide before counting
        unsigned prev = atomicAdd(counter, 1u);
        last = (prev == NBLOCKS - 1);
    }
    __syncthreads();
    if (!last) return;

    // This block arrived last: all 2048 partials are visible. Reduce them
    // in fixed order -> deterministic.
    __threadfence();  // acquire side
    float a = 0.0f;
    #pragma unroll
    for (int k = 0; k < NBLOCKS / NTHREADS; ++k)
        a += partial[threadIdx.x + k * NTHREADS];
    #pragma unroll
    for (int off = 32; off > 0; off >>= 1)
        a += __shfl_down(a, off, 64);
    if (lane == 0) s[wid] = a;
    __syncthreads();
    if (threadIdx.x == 0)
        out[0] = ((s[0] + s[1]) + (s[2] + s[3])) / (float)N_TOTAL;
}

extern "C" void kernel_launch(void* const* d_in, const int* in_sizes, int n_in,
                              void* d_out, int out_size, void* d_ws, size_t ws_size,
                              hipStream_t stream) {
    const float4* pred = (const float4*)d_in[0];
    const float4* mask = (const float4*)d_in[1];
    float* out = (float*)d_out;
    float* partial = (float*)d_ws;                       // 2048 floats
    unsigned* counter = (unsigned*)((char*)d_ws + NBLOCKS * sizeof(float));

    hipMemsetAsync(counter, 0, sizeof(unsigned), stream);
    abs_diff_mean<<<NBLOCKS, NTHREADS, 0, stream>>>(pred, mask, partial,
                                                    counter, out);
}

// Round 4
// 26.080 us; speedup vs baseline: 3.3760x; 3.3760x over previous
//
#include <hip/hip_runtime.h>

// out[0] = mean(|pred - mask|) over 16Mi fp32 elements (the Gaussian-conv
// loop in the reference is dead code). Memory-bound streaming reduction.
//
// Round-4: two-kernel structure (round-3's fence+counter fusion collapsed to
// 1 TB/s -- device-scope fences thrash per-XCD L2s; never again). Main kernel
// is now a static block-contiguous partition: block b owns chunk of
// 2048 float4 (32 KB) per input; each thread issues 8 float4 loads at 4 KB
// stride, all staged before compute. vs round-2's failed version: stride is
// 4 KB block-local, not 8 MB grid-global (channel camping).

#define N_TOTAL (16u * 1024u * 1024u)   // 16,777,216 elements
#define NTHREADS 256
#define NBLOCKS  2048
#define PER_THREAD 8
#define CHUNK (NTHREADS * PER_THREAD)   // 2048 float4 per block per input

__global__ __launch_bounds__(NTHREADS) void abs_diff_partial(
    const float4* __restrict__ pred,
    const float4* __restrict__ mask,
    float* __restrict__ partial) {
    const unsigned base = blockIdx.x * CHUNK + threadIdx.x;

    float4 p[PER_THREAD], m[PER_THREAD];
    #pragma unroll
    for (int k = 0; k < PER_THREAD; ++k) p[k] = pred[base + k * NTHREADS];
    #pragma unroll
    for (int k = 0; k < PER_THREAD; ++k) m[k] = mask[base + k * NTHREADS];

    float a0 = 0.f, a1 = 0.f, a2 = 0.f, a3 = 0.f;
    #pragma unroll
    for (int k = 0; k < PER_THREAD; ++k) {
        a0 += fabsf(p[k].x - m[k].x);
        a1 += fabsf(p[k].y - m[k].y);
        a2 += fabsf(p[k].z - m[k].z);
        a3 += fabsf(p[k].w - m[k].w);
    }
    float acc = (a0 + a1) + (a2 + a3);

    // wave-64 shuffle reduce
    #pragma unroll
    for (int off = 32; off > 0; off >>= 1)
        acc += __shfl_down(acc, off, 64);

    __shared__ float s[NTHREADS / 64];
    const int lane = threadIdx.x & 63;
    const int wid  = threadIdx.x >> 6;
    if (lane == 0) s[wid] = acc;
    __syncthreads();
    if (threadIdx.x == 0)
        partial[blockIdx.x] = (s[0] + s[1]) + (s[2] + s[3]);  // fixed order
}

__global__ __launch_bounds__(NTHREADS) void final_reduce(
    const float* __restrict__ partial, float* __restrict__ out) {
    float acc = 0.0f;
    #pragma unroll
    for (int k = 0; k < NBLOCKS / NTHREADS; ++k)
        acc += partial[threadIdx.x + k * NTHREADS];
    #pragma unroll
    for (int off = 32; off > 0; off >>= 1)
        acc += __shfl_down(acc, off, 64);

    __shared__ float s[NTHREADS / 64];
    const int lane = threadIdx.x & 63;
    const int wid  = threadIdx.x >> 6;
    if (lane == 0) s[wid] = acc;
    __syncthreads();
    if (threadIdx.x == 0)
        out[0] = ((s[0] + s[1]) + (s[2] + s[3])) / (float)N_TOTAL;
}

extern "C" void kernel_launch(void* const* d_in, const int* in_sizes, int n_in,
                              void* d_out, int out_size, void* d_ws, size_t ws_size,
                              hipStream_t stream) {
    const float4* pred = (const float4*)d_in[0];
    const float4* mask = (const float4*)d_in[1];
    float* out = (float*)d_out;
    float* partial = (float*)d_ws;  // NBLOCKS floats = 8 KB scratch

    abs_diff_partial<<<NBLOCKS, NTHREADS, 0, stream>>>(pred, mask, partial);
    final_reduce<<<1, NTHREADS, 0, stream>>>(partial, out);
}